// Round 1
// baseline (3422.726 us; speedup 1.0000x reference)
//
#include <hip/hip_runtime.h>
#include <stdint.h>

// RNN ensemble: M=2048 models, N=128, A=4 conditions, 5 phases x 50 steps.
// Block = one model pair (p, p+1024), 256 threads (thread = (model,row)).
// W (both models) staged in LDS fp32 once, reused 250 steps.

struct __align__(16) Smem {
  float W[2][128][128];   // row-major, 16B-slot XOR-swizzled: (i,j) at slot (j>>2)^(i&7)
  float r[2][4][128];     // current state r[model][a][j]
  float red[4][8];        // per-wave projection partials
  uint2 skeys[250];       // per-step threefry keys (phase*50 + s)
};

__device__ __forceinline__ void tfround(uint32_t& x0, uint32_t& x1, const int r) {
  x0 += x1;
  x1 = (x1 << r) | (x1 >> (32 - r));
  x1 ^= x0;
}

// JAX threefry2x32 (20 rounds), matches jax/_src/prng.py lowering exactly.
__device__ __forceinline__ uint2 threefry(uint32_t k0, uint32_t k1, uint32_t c0, uint32_t c1) {
  uint32_t k2 = k0 ^ k1 ^ 0x1BD11BDAu;
  uint32_t x0 = c0 + k0, x1 = c1 + k1;
  tfround(x0,x1,13); tfround(x0,x1,15); tfround(x0,x1,26); tfround(x0,x1,6);
  x0 += k1; x1 += k2 + 1u;
  tfround(x0,x1,17); tfround(x0,x1,29); tfround(x0,x1,16); tfround(x0,x1,24);
  x0 += k2; x1 += k0 + 2u;
  tfround(x0,x1,13); tfround(x0,x1,15); tfround(x0,x1,26); tfround(x0,x1,6);
  x0 += k0; x1 += k1 + 3u;
  tfround(x0,x1,17); tfround(x0,x1,29); tfround(x0,x1,16); tfround(x0,x1,24);
  x0 += k1; x1 += k2 + 4u;
  tfround(x0,x1,13); tfround(x0,x1,15); tfround(x0,x1,26); tfround(x0,x1,6);
  x0 += k2; x1 += k0 + 5u;
  return make_uint2(x0, x1);
}

__device__ __forceinline__ float unit_from_bits(uint32_t bits) {
  return __uint_as_float((bits >> 9) | 0x3f800000u) - 1.0f;
}

__global__ __launch_bounds__(256) void rnn_kernel(
    const float* __restrict__ x,
    const float* __restrict__ rec_w,
    const float* __restrict__ rec_b,
    const float* __restrict__ inp_w,
    const float* __restrict__ out_w,
    const float* __restrict__ mem_w,
    float* __restrict__ out) {
  __shared__ Smem sm;
  const int t = threadIdx.x;
  const int pair = blockIdx.x;          // 0..1023
  const int model = t >> 7;             // 0 or 1
  const int i = t & 127;                // row
  const int m = pair + model * 1024;    // global model id
  const int sw = i & 7;

  // --- step keys: partitionable threefry key chain ---
  // root = (0,42); phase key p = threefry(root; 0, p); step key = threefry(kp; 0, s)
  if (t < 250) {
    int p = t / 50, s = t - p * 50;
    uint2 pk = threefry(0u, 42u, 0u, (uint32_t)p);
    sm.skeys[t] = threefry(pk.x, pk.y, 0u, (uint32_t)s);
  }

  // --- stage W: coalesced global float4, swizzled LDS store ---
  for (int mdl = 0; mdl < 2; ++mdl) {
    const float* gw = rec_w + (size_t)(pair + mdl * 1024) * 16384;
    #pragma unroll
    for (int c = 0; c < 16; ++c) {
      int flat = c * 1024 + t * 4;
      float4 v = *reinterpret_cast<const float4*>(gw + flat);
      int ii = flat >> 7;
      int g = (flat & 127) >> 2;
      *reinterpret_cast<float4*>(&sm.W[mdl][ii][((g ^ (ii & 7)) << 2)]) = v;
    }
  }

  // --- per-thread constants ---
  const float bi = rec_b[m * 128 + i];
  const float w0 = inp_w[(m * 128 + i) * 2 + 0];
  const float w1 = inp_w[(m * 128 + i) * 2 + 1];
  float inpS[4], inpT[4];
  #pragma unroll
  for (int a = 0; a < 4; ++a) {
    inpS[a] = w0 * x[a * 4 + 0] + w1 * x[a * 4 + 1];  // x[a,0,:]
    inpT[a] = w0 * x[a * 4 + 2] + w1 * x[a * 4 + 3];  // x[a,1,:]
  }

  float rr[4] = {0.f, 0.f, 0.f, 0.f};
  #pragma unroll
  for (int a = 0; a < 4; ++a) sm.r[model][a][i] = 0.f;
  float rsD[4] = {0.f,0.f,0.f,0.f};
  float rsR[4] = {0.f,0.f,0.f,0.f};

  __syncthreads();

  const uint32_t nj = (uint32_t)(m * 128 + i);  // flat noise index

  for (int ph = 0; ph < 5; ++ph) {
    float cin[4];
    #pragma unroll
    for (int a = 0; a < 4; ++a)
      cin[a] = (ph == 1) ? inpS[a] : ((ph == 3) ? inpT[a] : 0.f);
    const bool phD = (ph == 2), phR = (ph == 4);

    for (int s = 0; s < 50; ++s) {
      // noise: bits = x0^x1 of threefry(step_key; 0, flat_idx)
      uint2 key = sm.skeys[ph * 50 + s];
      uint2 bb = threefry(key.x, key.y, 0u, nj);
      float nz = 0.1f * unit_from_bits(bb.x ^ bb.y);

      // pre[a][i] = sum_j W[i][j] * r[a][j]
      float a0=0.f,a1=0.f,a2=0.f,a3=0.f,b0=0.f,b1=0.f,b2=0.f,b3=0.f;
      const float* Wrow = &sm.W[model][i][0];
      const float* rb = &sm.r[model][0][0];
      #pragma unroll
      for (int g = 0; g < 32; g += 2) {
        {
          float4 w  = *reinterpret_cast<const float4*>(&Wrow[(g ^ sw) << 2]);
          float4 r0 = *reinterpret_cast<const float4*>(&rb[      g * 4]);
          float4 r1 = *reinterpret_cast<const float4*>(&rb[128 + g * 4]);
          float4 r2 = *reinterpret_cast<const float4*>(&rb[256 + g * 4]);
          float4 r3 = *reinterpret_cast<const float4*>(&rb[384 + g * 4]);
          a0 += w.x*r0.x; a0 += w.y*r0.y; a0 += w.z*r0.z; a0 += w.w*r0.w;
          a1 += w.x*r1.x; a1 += w.y*r1.y; a1 += w.z*r1.z; a1 += w.w*r1.w;
          a2 += w.x*r2.x; a2 += w.y*r2.y; a2 += w.z*r2.z; a2 += w.w*r2.w;
          a3 += w.x*r3.x; a3 += w.y*r3.y; a3 += w.z*r3.z; a3 += w.w*r3.w;
        }
        {
          int g1 = g + 1;
          float4 w  = *reinterpret_cast<const float4*>(&Wrow[(g1 ^ sw) << 2]);
          float4 r0 = *reinterpret_cast<const float4*>(&rb[      g1 * 4]);
          float4 r1 = *reinterpret_cast<const float4*>(&rb[128 + g1 * 4]);
          float4 r2 = *reinterpret_cast<const float4*>(&rb[256 + g1 * 4]);
          float4 r3 = *reinterpret_cast<const float4*>(&rb[384 + g1 * 4]);
          b0 += w.x*r0.x; b0 += w.y*r0.y; b0 += w.z*r0.z; b0 += w.w*r0.w;
          b1 += w.x*r1.x; b1 += w.y*r1.y; b1 += w.z*r1.z; b1 += w.w*r1.w;
          b2 += w.x*r2.x; b2 += w.y*r2.y; b2 += w.z*r2.z; b2 += w.w*r2.w;
          b3 += w.x*r3.x; b3 += w.y*r3.y; b3 += w.z*r3.z; b3 += w.w*r3.w;
        }
      }
      float acc[4] = {a0+b0, a1+b1, a2+b2, a3+b3};

      __syncthreads();  // all dot-reads of sm.r complete

      #pragma unroll
      for (int a = 0; a < 4; ++a) {
        float pre = acc[a] + bi + cin[a];
        float rl = fmaxf(pre, 0.f);
        float dr = ((-rr[a]) + rl + nz) * 0.2f;   // C = dt/tau = 0.2
        rr[a] = rr[a] + dr;
        sm.r[model][a][i] = rr[a];
        if (phD && s >= 25) rsD[a] += rr[a];
        if (phR)            rsR[a] += rr[a];
      }
      __syncthreads();  // r updated for next step
    }

    // phase-end projections (linear => project the accumulated sum once)
    if (ph == 2 || ph == 4) {
      const float* pw = (ph == 2) ? mem_w : out_w;
      const float denom = (ph == 2) ? 25.0f : 50.0f;
      const int sel = (ph == 2) ? 0 : 1;
      float wv0 = pw[(m * 2 + 0) * 128 + i];
      float wv1 = pw[(m * 2 + 1) * 128 + i];
      float vals[8];
      #pragma unroll
      for (int a = 0; a < 4; ++a) {
        float rs = (ph == 2) ? rsD[a] : rsR[a];
        vals[a * 2 + 0] = rs * wv0;
        vals[a * 2 + 1] = rs * wv1;
      }
      #pragma unroll
      for (int v = 0; v < 8; ++v) {
        float xv = vals[v];
        #pragma unroll
        for (int off = 1; off < 64; off <<= 1)
          xv += __shfl_xor(xv, off, 64);
        vals[v] = xv;
      }
      if ((t & 63) == 0) {
        #pragma unroll
        for (int v = 0; v < 8; ++v) sm.red[t >> 6][v] = vals[v];
      }
      __syncthreads();
      if (t < 16) {
        int mdl = t >> 3, v = t & 7;
        int a = v >> 1, o = v & 1;
        float sumv = sm.red[mdl * 2][v] + sm.red[mdl * 2 + 1][v];
        int mm = pair + mdl * 1024;
        out[(((size_t)sel * 4 + a) * 2048 + mm) * 2 + o] = sumv / denom;
      }
      __syncthreads();
    }
  }
}

extern "C" void kernel_launch(void* const* d_in, const int* in_sizes, int n_in,
                              void* d_out, int out_size, void* d_ws, size_t ws_size,
                              hipStream_t stream) {
  (void)in_sizes; (void)n_in; (void)d_ws; (void)ws_size; (void)out_size;
  const float* x     = (const float*)d_in[0];
  const float* rec_w = (const float*)d_in[1];
  const float* rec_b = (const float*)d_in[2];
  const float* inp_w = (const float*)d_in[3];
  const float* out_w = (const float*)d_in[4];
  const float* mem_w = (const float*)d_in[5];
  rnn_kernel<<<1024, 256, 0, stream>>>(x, rec_w, rec_b, inp_w, out_w, mem_w, (float*)d_out);
}

// Round 2
// 1970.596 us; speedup vs baseline: 1.7369x; 1.7369x over previous
//
#include <hip/hip_runtime.h>
#include <stdint.h>

// RNN ensemble: M=2048 models, N=128, A=4 conditions, 5 phases x 50 steps.
// Block = ONE model, 256 threads: thread = (row i = t>>1, half h = t&1).
// W row-half (64 floats) lives in REGISTERS; r state double-buffered in LDS
// (one barrier per step). Halves combine via shfl_xor(1); both halves keep
// the full 4-condition row state redundantly (identical rounding).

struct __align__(16) Smem {
  float rbuf[2][4][128];   // [parity][condition][row]
  uint2 skeys[250];        // per-step threefry keys
  float red[4][8];         // [wave][o*4+a] projection partials
};

__device__ __forceinline__ void tfround(uint32_t& x0, uint32_t& x1, const int r) {
  x0 += x1;
  x1 = (x1 << r) | (x1 >> (32 - r));
  x1 ^= x0;
}

// JAX threefry2x32 (20 rounds), matches jax/_src/prng.py lowering exactly.
__device__ __forceinline__ uint2 threefry(uint32_t k0, uint32_t k1, uint32_t c0, uint32_t c1) {
  uint32_t k2 = k0 ^ k1 ^ 0x1BD11BDAu;
  uint32_t x0 = c0 + k0, x1 = c1 + k1;
  tfround(x0,x1,13); tfround(x0,x1,15); tfround(x0,x1,26); tfround(x0,x1,6);
  x0 += k1; x1 += k2 + 1u;
  tfround(x0,x1,17); tfround(x0,x1,29); tfround(x0,x1,16); tfround(x0,x1,24);
  x0 += k2; x1 += k0 + 2u;
  tfround(x0,x1,13); tfround(x0,x1,15); tfround(x0,x1,26); tfround(x0,x1,6);
  x0 += k0; x1 += k1 + 3u;
  tfround(x0,x1,17); tfround(x0,x1,29); tfround(x0,x1,16); tfround(x0,x1,24);
  x0 += k1; x1 += k2 + 4u;
  tfround(x0,x1,13); tfround(x0,x1,15); tfround(x0,x1,26); tfround(x0,x1,6);
  x0 += k2; x1 += k0 + 5u;
  return make_uint2(x0, x1);
}

__device__ __forceinline__ float unit_from_bits(uint32_t bits) {
  return __uint_as_float((bits >> 9) | 0x3f800000u) - 1.0f;
}

__global__ __launch_bounds__(256, 4) void rnn_kernel(
    const float* __restrict__ x,
    const float* __restrict__ rec_w,
    const float* __restrict__ rec_b,
    const float* __restrict__ inp_w,
    const float* __restrict__ out_w,
    const float* __restrict__ mem_w,
    float* __restrict__ out) {
  __shared__ Smem sm;
  const int t = threadIdx.x;
  const int m = blockIdx.x;           // model 0..2047
  const int i = t >> 1;               // row 0..127
  const int h = t & 1;                // half 0/1 (j in [h*64, h*64+64))

  // --- step keys: root=(0,42); phase p key = tf(root;0,p); step key = tf(kp;0,s)
  if (t < 250) {
    int p = t / 50, s = t - p * 50;
    uint2 pk = threefry(0u, 42u, 0u, (uint32_t)p);
    sm.skeys[t] = threefry(pk.x, pk.y, 0u, (uint32_t)s);
  }

  // --- W row-half into registers (one-time; lines fully consumed per thread)
  float4 w[16];
  {
    const float* gw = rec_w + (size_t)m * 16384 + (size_t)i * 128 + h * 64;
    #pragma unroll
    for (int jj = 0; jj < 16; ++jj)
      w[jj] = *reinterpret_cast<const float4*>(gw + jj * 4);
  }

  // --- per-thread constants ---
  const float bi = rec_b[m * 128 + i];
  const float w0 = inp_w[(m * 128 + i) * 2 + 0];
  const float w1 = inp_w[(m * 128 + i) * 2 + 1];
  float inpS[4], inpT[4];
  #pragma unroll
  for (int a = 0; a < 4; ++a) {
    inpS[a] = w0 * x[a * 4 + 0] + w1 * x[a * 4 + 1];  // x[a,0,:]
    inpT[a] = w0 * x[a * 4 + 2] + w1 * x[a * 4 + 3];  // x[a,1,:]
  }

  float rr[4] = {0.f, 0.f, 0.f, 0.f};
  float rsD[4] = {0.f, 0.f, 0.f, 0.f};
  float rsR[4] = {0.f, 0.f, 0.f, 0.f};
  // init parity-0 buffer (each thread writes 2 of the 4 conditions for its row)
  sm.rbuf[0][2 * h + 0][i] = 0.f;
  sm.rbuf[0][2 * h + 1][i] = 0.f;

  __syncthreads();

  const uint32_t nj = (uint32_t)(m * 128 + i);  // flat noise index (per model,row)

  for (int ph = 0; ph < 5; ++ph) {
    float cc[4];
    #pragma unroll
    for (int a = 0; a < 4; ++a)
      cc[a] = bi + ((ph == 1) ? inpS[a] : ((ph == 3) ? inpT[a] : 0.f));
    const bool phD = (ph == 2), phR = (ph == 4);

    for (int s = 0; s < 50; ++s) {
      const int gs = ph * 50 + s;
      const int p = gs & 1;

      // noise: bits = x0^x1 of threefry(step_key; 0, flat_idx)
      uint2 key = sm.skeys[gs];
      uint2 bb = threefry(key.x, key.y, 0u, nj);
      float nz = 0.1f * unit_from_bits(bb.x ^ bb.y);

      // partial dots over this thread's 64 columns (W in regs, r broadcast-read)
      float a0 = 0.f, a1 = 0.f, a2 = 0.f, a3 = 0.f;
      const float* rb = &sm.rbuf[p][0][h * 64];
      #pragma unroll
      for (int jj = 0; jj < 16; ++jj) {
        float4 w4 = w[jj];
        float4 r0 = *reinterpret_cast<const float4*>(rb + jj * 4);
        float4 r1 = *reinterpret_cast<const float4*>(rb + 128 + jj * 4);
        float4 r2 = *reinterpret_cast<const float4*>(rb + 256 + jj * 4);
        float4 r3 = *reinterpret_cast<const float4*>(rb + 384 + jj * 4);
        a0 += w4.x * r0.x; a0 += w4.y * r0.y; a0 += w4.z * r0.z; a0 += w4.w * r0.w;
        a1 += w4.x * r1.x; a1 += w4.y * r1.y; a1 += w4.z * r1.z; a1 += w4.w * r1.w;
        a2 += w4.x * r2.x; a2 += w4.y * r2.y; a2 += w4.z * r2.z; a2 += w4.w * r2.w;
        a3 += w4.x * r3.x; a3 += w4.y * r3.y; a3 += w4.z * r3.z; a3 += w4.w * r3.w;
      }
      float acc[4] = {a0, a1, a2, a3};
      // combine halves (both lanes get identical rounding: a+b == b+a)
      #pragma unroll
      for (int a = 0; a < 4; ++a)
        acc[a] += __shfl_xor(acc[a], 1, 64);

      #pragma unroll
      for (int a = 0; a < 4; ++a) {
        float pre = acc[a] + cc[a];
        float rl = fmaxf(pre, 0.f);
        float dr = ((-rr[a]) + rl + nz) * 0.2f;   // C = dt/tau = 0.2
        rr[a] = rr[a] + dr;
        if (phD && s >= 25) rsD[a] += rr[a];
        if (phR)            rsR[a] += rr[a];
      }
      // write next-parity buffer: thread writes conditions {2h, 2h+1} for row i
      sm.rbuf[p ^ 1][2 * h + 0][i] = rr[2 * h + 0];
      sm.rbuf[p ^ 1][2 * h + 1][i] = rr[2 * h + 1];

      __syncthreads();  // next step reads p^1; writes to p resume after this
    }

    // phase-end projection of accumulated state sums (linear => project once)
    if (ph == 2 || ph == 4) {
      const float* pw = (ph == 2) ? mem_w : out_w;
      const float denom = (ph == 2) ? 25.0f : 50.0f;
      const int sel = (ph == 2) ? 0 : 1;
      // output channel o = h; weight pw[m][o][i]
      const float wv = pw[((size_t)m * 2 + h) * 128 + i];
      float c[4];
      #pragma unroll
      for (int a = 0; a < 4; ++a)
        c[a] = ((ph == 2) ? rsD[a] : rsR[a]) * wv;
      // reduce over rows within wave, keeping h classes separate (skip offset 1)
      #pragma unroll
      for (int a = 0; a < 4; ++a) {
        #pragma unroll
        for (int off = 2; off < 64; off <<= 1)
          c[a] += __shfl_xor(c[a], off, 64);
      }
      if ((t & 63) < 2) {
        #pragma unroll
        for (int a = 0; a < 4; ++a)
          sm.red[t >> 6][h * 4 + a] = c[a];
      }
      __syncthreads();
      if (t < 8) {
        int a = t >> 1, o = t & 1;
        float v = sm.red[0][o * 4 + a] + sm.red[1][o * 4 + a] +
                  sm.red[2][o * 4 + a] + sm.red[3][o * 4 + a];
        out[(((size_t)sel * 4 + a) * 2048 + m) * 2 + o] = v / denom;
      }
      // no trailing barrier needed: sm.red not touched again for >=50 steps
    }
  }
}

extern "C" void kernel_launch(void* const* d_in, const int* in_sizes, int n_in,
                              void* d_out, int out_size, void* d_ws, size_t ws_size,
                              hipStream_t stream) {
  (void)in_sizes; (void)n_in; (void)d_ws; (void)ws_size; (void)out_size;
  const float* x     = (const float*)d_in[0];
  const float* rec_w = (const float*)d_in[1];
  const float* rec_b = (const float*)d_in[2];
  const float* inp_w = (const float*)d_in[3];
  const float* out_w = (const float*)d_in[4];
  const float* mem_w = (const float*)d_in[5];
  rnn_kernel<<<2048, 256, 0, stream>>>(x, rec_w, rec_b, inp_w, out_w, mem_w, (float*)d_out);
}

// Round 3
// 1223.560 us; speedup vs baseline: 2.7974x; 1.6105x over previous
//
#include <hip/hip_runtime.h>
#include <stdint.h>

// RNN ensemble: M=2048 models, N=128, A=4 conditions, 5 phases x 50 steps.
// Block = ONE model, 256 threads: thread = (row i = t>>1, half h = t&1).
// W row-half (64 floats) in registers; r state double-buffered in LDS with
// BANK-DISJOINT padded layout: cond row = 136 words, h=1 half at word 68
// (+4 banks vs h=0) so each wave read's two addresses never collide.
// Threefry deduped: lane h computes noise for step s+h, pair swaps via shfl.

#define RSTRIDE 136   // words per cond row (h0 at 0..63, h1 at 68..131)
#define H1OFF    68

struct __align__(16) Smem {
  float rbuf[2][4 * RSTRIDE];  // [parity][cond*136 + padded j]
  uint2 skeys[250];            // per-step threefry keys
  float red[4][8];             // [wave][o*4+a] projection partials
};

__device__ __forceinline__ void tfround(uint32_t& x0, uint32_t& x1, const int r) {
  x0 += x1;
  x1 = (x1 << r) | (x1 >> (32 - r));
  x1 ^= x0;
}

// JAX threefry2x32 (20 rounds), matches jax/_src/prng.py lowering exactly.
__device__ __forceinline__ uint2 threefry(uint32_t k0, uint32_t k1, uint32_t c0, uint32_t c1) {
  uint32_t k2 = k0 ^ k1 ^ 0x1BD11BDAu;
  uint32_t x0 = c0 + k0, x1 = c1 + k1;
  tfround(x0,x1,13); tfround(x0,x1,15); tfround(x0,x1,26); tfround(x0,x1,6);
  x0 += k1; x1 += k2 + 1u;
  tfround(x0,x1,17); tfround(x0,x1,29); tfround(x0,x1,16); tfround(x0,x1,24);
  x0 += k2; x1 += k0 + 2u;
  tfround(x0,x1,13); tfround(x0,x1,15); tfround(x0,x1,26); tfround(x0,x1,6);
  x0 += k0; x1 += k1 + 3u;
  tfround(x0,x1,17); tfround(x0,x1,29); tfround(x0,x1,16); tfround(x0,x1,24);
  x0 += k1; x1 += k2 + 4u;
  tfround(x0,x1,13); tfround(x0,x1,15); tfround(x0,x1,26); tfround(x0,x1,6);
  x0 += k2; x1 += k0 + 5u;
  return make_uint2(x0, x1);
}

__device__ __forceinline__ float unit_from_bits(uint32_t bits) {
  return __uint_as_float((bits >> 9) | 0x3f800000u) - 1.0f;
}

__global__ __launch_bounds__(256, 4) void rnn_kernel(
    const float* __restrict__ x,
    const float* __restrict__ rec_w,
    const float* __restrict__ rec_b,
    const float* __restrict__ inp_w,
    const float* __restrict__ out_w,
    const float* __restrict__ mem_w,
    float* __restrict__ out) {
  __shared__ Smem sm;
  const int t = threadIdx.x;
  const int m = blockIdx.x;           // model 0..2047
  const int i = t >> 1;               // row 0..127
  const int h = t & 1;                // half 0/1 (j in [h*64, h*64+64))

  // --- step keys: root=(0,42); phase p key = tf(root;0,p); step key = tf(kp;0,s)
  if (t < 250) {
    int p = t / 50, s = t - p * 50;
    uint2 pk = threefry(0u, 42u, 0u, (uint32_t)p);
    sm.skeys[t] = threefry(pk.x, pk.y, 0u, (uint32_t)s);
  }

  // --- W row-half into registers
  float4 w[16];
  {
    const float* gw = rec_w + (size_t)m * 16384 + (size_t)i * 128 + h * 64;
    #pragma unroll
    for (int jj = 0; jj < 16; ++jj)
      w[jj] = *reinterpret_cast<const float4*>(gw + jj * 4);
  }

  // --- per-thread constants ---
  const float bi = rec_b[m * 128 + i];
  const float w0 = inp_w[(m * 128 + i) * 2 + 0];
  const float w1 = inp_w[(m * 128 + i) * 2 + 1];
  float inpS[4], inpT[4];
  #pragma unroll
  for (int a = 0; a < 4; ++a) {
    inpS[a] = w0 * x[a * 4 + 0] + w1 * x[a * 4 + 1];  // x[a,0,:]
    inpT[a] = w0 * x[a * 4 + 2] + w1 * x[a * 4 + 3];  // x[a,1,:]
  }

  float rr[4] = {0.f, 0.f, 0.f, 0.f};
  float rsD[4] = {0.f, 0.f, 0.f, 0.f};
  float rsR[4] = {0.f, 0.f, 0.f, 0.f};

  const int iw = i + (i >= 64 ? 4 : 0);   // padded j position for row i
  // init parity-0 buffer (thread writes conds {2h,2h+1} for its row)
  sm.rbuf[0][(2 * h + 0) * RSTRIDE + iw] = 0.f;
  sm.rbuf[0][(2 * h + 1) * RSTRIDE + iw] = 0.f;

  __syncthreads();

  const uint32_t nj = (uint32_t)(m * 128 + i);  // flat noise index (model,row)

  for (int ph = 0; ph < 5; ++ph) {
    float cc[4];
    #pragma unroll
    for (int a = 0; a < 4; ++a)
      cc[a] = bi + ((ph == 1) ? inpS[a] : ((ph == 3) ? inpT[a] : 0.f));
    const bool phD = (ph == 2), phR = (ph == 4);

    for (int sp = 0; sp < 25; ++sp) {
      // --- noise for steps 2sp (parity 0) and 2sp+1: lane h computes step 2sp+h
      float nzA, nzB;
      {
        uint2 key = sm.skeys[ph * 50 + 2 * sp + h];
        uint2 bb = threefry(key.x, key.y, 0u, nj);
        uint32_t mybits = bb.x ^ bb.y;
        uint32_t obits = __shfl_xor(mybits, 1, 64);
        uint32_t bitsA = h ? obits : mybits;   // step 2sp
        uint32_t bitsB = h ? mybits : obits;   // step 2sp+1
        nzA = 0.1f * unit_from_bits(bitsA);
        nzB = 0.1f * unit_from_bits(bitsB);
      }

      #pragma unroll
      for (int half = 0; half < 2; ++half) {
        const int p = half;                 // read parity (ph*50 even => p = s&1)
        const float nz = half ? nzB : nzA;
        const int s = 2 * sp + half;

        // partial dots over this thread's 64 columns
        float a0 = 0.f, a1 = 0.f, a2 = 0.f, a3 = 0.f;
        const float* rb = &sm.rbuf[p][h * H1OFF];
        #pragma unroll
        for (int jj = 0; jj < 16; ++jj) {
          float4 w4 = w[jj];
          float4 r0 = *reinterpret_cast<const float4*>(rb + 0 * RSTRIDE + jj * 4);
          float4 r1 = *reinterpret_cast<const float4*>(rb + 1 * RSTRIDE + jj * 4);
          float4 r2 = *reinterpret_cast<const float4*>(rb + 2 * RSTRIDE + jj * 4);
          float4 r3 = *reinterpret_cast<const float4*>(rb + 3 * RSTRIDE + jj * 4);
          a0 += w4.x * r0.x; a0 += w4.y * r0.y; a0 += w4.z * r0.z; a0 += w4.w * r0.w;
          a1 += w4.x * r1.x; a1 += w4.y * r1.y; a1 += w4.z * r1.z; a1 += w4.w * r1.w;
          a2 += w4.x * r2.x; a2 += w4.y * r2.y; a2 += w4.z * r2.z; a2 += w4.w * r2.w;
          a3 += w4.x * r3.x; a3 += w4.y * r3.y; a3 += w4.z * r3.z; a3 += w4.w * r3.w;
        }
        float acc[4] = {a0, a1, a2, a3};
        // combine halves (both lanes get identical rounding: a+b == b+a)
        #pragma unroll
        for (int a = 0; a < 4; ++a)
          acc[a] += __shfl_xor(acc[a], 1, 64);

        #pragma unroll
        for (int a = 0; a < 4; ++a) {
          float pre = acc[a] + cc[a];
          float rl = fmaxf(pre, 0.f);
          float dr = ((-rr[a]) + rl + nz) * 0.2f;   // C = dt/tau = 0.2
          rr[a] = rr[a] + dr;
          if (phD && s >= 25) rsD[a] += rr[a];
          if (phR)            rsR[a] += rr[a];
        }
        // write next-parity buffer (bank-disjoint padded layout)
        sm.rbuf[p ^ 1][(2 * h + 0) * RSTRIDE + iw] = rr[2 * h + 0];
        sm.rbuf[p ^ 1][(2 * h + 1) * RSTRIDE + iw] = rr[2 * h + 1];

        __syncthreads();
      }
    }

    // phase-end projection of accumulated state sums (linear => project once)
    if (ph == 2 || ph == 4) {
      const float* pw = (ph == 2) ? mem_w : out_w;
      const float denom = (ph == 2) ? 25.0f : 50.0f;
      const int sel = (ph == 2) ? 0 : 1;
      // output channel o = h; weight pw[m][o][i]
      const float wv = pw[((size_t)m * 2 + h) * 128 + i];
      float c[4];
      #pragma unroll
      for (int a = 0; a < 4; ++a)
        c[a] = ((ph == 2) ? rsD[a] : rsR[a]) * wv;
      // reduce over rows within wave, keeping h classes separate (skip offset 1)
      #pragma unroll
      for (int a = 0; a < 4; ++a) {
        #pragma unroll
        for (int off = 2; off < 64; off <<= 1)
          c[a] += __shfl_xor(c[a], off, 64);
      }
      if ((t & 63) < 2) {
        #pragma unroll
        for (int a = 0; a < 4; ++a)
          sm.red[t >> 6][h * 4 + a] = c[a];
      }
      __syncthreads();
      if (t < 8) {
        int a = t >> 1, o = t & 1;
        float v = sm.red[0][o * 4 + a] + sm.red[1][o * 4 + a] +
                  sm.red[2][o * 4 + a] + sm.red[3][o * 4 + a];
        out[(((size_t)sel * 4 + a) * 2048 + m) * 2 + o] = v / denom;
      }
      // no trailing barrier needed: sm.red not touched again for >=50 steps
    }
  }
}

extern "C" void kernel_launch(void* const* d_in, const int* in_sizes, int n_in,
                              void* d_out, int out_size, void* d_ws, size_t ws_size,
                              hipStream_t stream) {
  (void)in_sizes; (void)n_in; (void)d_ws; (void)ws_size; (void)out_size;
  const float* x     = (const float*)d_in[0];
  const float* rec_w = (const float*)d_in[1];
  const float* rec_b = (const float*)d_in[2];
  const float* inp_w = (const float*)d_in[3];
  const float* out_w = (const float*)d_in[4];
  const float* mem_w = (const float*)d_in[5];
  rnn_kernel<<<2048, 256, 0, stream>>>(x, rec_w, rec_b, inp_w, out_w, mem_w, (float*)d_out);
}

// Round 4
// 730.883 us; speedup vs baseline: 4.6830x; 1.6741x over previous
//
#include <hip/hip_runtime.h>
#include <stdint.h>

// RNN ensemble: M=2048 models, N=128, A=4 conds, 5 phases x 50 steps.
// Block = 1 model, 4 waves. Wave w owns M-tiles 2w,2w+1 (rows 32w..32w+31).
// pre[128x4] = W @ r via mfma_f32_16x16x32_bf16 with hi/lo bf16 split:
//   B cols 0-3 = rhi (4 conds), cols 4-7 = rlo, cols 8-15 = 0.
//   acc = Whi@B then += Wlo@B  =>  cols0-3 = W@rhi, cols4-7 = W@rlo.
//   pre = col_c + col_{c+4} via shfl_xor(4). Error ~2^-17 relative (fp32-class).
// W frags persist in VGPRs (64 regs). r fragments round-trip through a
// double-buffered 2KB LDS buffer stored in B-fragment order (4 ds_read_b128
// per wave-step). Noise threefry: 64 lanes produce 32 rows x 2 steps.

typedef __attribute__((ext_vector_type(8))) short bf16x8;
typedef __attribute__((ext_vector_type(4))) float f32x4;

struct __align__(16) Smem {
  unsigned short bfrag[2][4][4][8][8]; // [parity][q][kg][n(<8)][e] bf16, 4KB
  float nbuf[2][128];                  // [substep][row] noise, 1KB
  uint2 skeys[250];
  float red[4][4][2];                  // [wave][cond][o]
};

__device__ __forceinline__ void tfround(uint32_t& x0, uint32_t& x1, const int r) {
  x0 += x1;
  x1 = (x1 << r) | (x1 >> (32 - r));
  x1 ^= x0;
}

// JAX threefry2x32 (20 rounds)
__device__ __forceinline__ uint2 threefry(uint32_t k0, uint32_t k1, uint32_t c0, uint32_t c1) {
  uint32_t k2 = k0 ^ k1 ^ 0x1BD11BDAu;
  uint32_t x0 = c0 + k0, x1 = c1 + k1;
  tfround(x0,x1,13); tfround(x0,x1,15); tfround(x0,x1,26); tfround(x0,x1,6);
  x0 += k1; x1 += k2 + 1u;
  tfround(x0,x1,17); tfround(x0,x1,29); tfround(x0,x1,16); tfround(x0,x1,24);
  x0 += k2; x1 += k0 + 2u;
  tfround(x0,x1,13); tfround(x0,x1,15); tfround(x0,x1,26); tfround(x0,x1,6);
  x0 += k0; x1 += k1 + 3u;
  tfround(x0,x1,17); tfround(x0,x1,29); tfround(x0,x1,16); tfround(x0,x1,24);
  x0 += k1; x1 += k2 + 4u;
  tfround(x0,x1,13); tfround(x0,x1,15); tfround(x0,x1,26); tfround(x0,x1,6);
  x0 += k2; x1 += k0 + 5u;
  return make_uint2(x0, x1);
}

__device__ __forceinline__ float unit_from_bits(uint32_t bits) {
  return __uint_as_float((bits >> 9) | 0x3f800000u) - 1.0f;
}

__device__ __forceinline__ unsigned short f2bf(float f) {
  uint32_t u = __float_as_uint(f);
  uint32_t r = u + 0x7fffu + ((u >> 16) & 1u);   // RNE (non-NaN inputs)
  return (unsigned short)(r >> 16);
}
__device__ __forceinline__ float bf2f(unsigned short b) {
  return __uint_as_float(((uint32_t)b) << 16);
}

__global__ __launch_bounds__(256, 3) void rnn_kernel(
    const float* __restrict__ x,
    const float* __restrict__ rec_w,
    const float* __restrict__ rec_b,
    const float* __restrict__ inp_w,
    const float* __restrict__ out_w,
    const float* __restrict__ mem_w,
    float* __restrict__ out) {
  __shared__ Smem sm;
  const int t = threadIdx.x;
  const int m = blockIdx.x;
  const int w = t >> 6;          // wave 0..3
  const int lane = t & 63;
  const int n = lane & 15;       // A-row / B-col / C-col index within tile
  const int kg = lane >> 4;      // k-group (0..3)
  const int c = n & 3;           // cond id for valid lanes (n<4)

  // step keys
  if (t < 250) {
    int p = t / 50, s = t - p * 50;
    uint2 pk = threefry(0u, 42u, 0u, (uint32_t)p);
    sm.skeys[t] = threefry(pk.x, pk.y, 0u, (uint32_t)s);
  }
  // zero parity-0 fragment buffer (2048B; 256 threads x 8B)
  {
    unsigned short* bz = &sm.bfrag[0][0][0][0][0];
    *reinterpret_cast<uint2*>(bz + t * 4) = make_uint2(0u, 0u);
  }

  // --- W fragments into registers: whi/wlo[t2][q], row = 32w+16*t2+n, k = 32q+8kg+e
  bf16x8 whi[2][4], wlo[2][4];
  #pragma unroll
  for (int t2 = 0; t2 < 2; ++t2) {
    const int rowA = 32 * w + 16 * t2 + n;
    const float* gp = rec_w + (size_t)m * 16384 + (size_t)rowA * 128 + 8 * kg;
    #pragma unroll
    for (int q = 0; q < 4; ++q) {
      float4 f0 = *reinterpret_cast<const float4*>(gp + 32 * q);
      float4 f1 = *reinterpret_cast<const float4*>(gp + 32 * q + 4);
      float fv[8] = {f0.x, f0.y, f0.z, f0.w, f1.x, f1.y, f1.z, f1.w};
      bf16x8 vh, vl;
      #pragma unroll
      for (int e = 0; e < 8; ++e) {
        unsigned short hb = f2bf(fv[e]);
        vh[e] = (short)hb;
        vl[e] = (short)f2bf(fv[e] - bf2f(hb));
      }
      whi[t2][q] = vh;
      wlo[t2][q] = vl;
    }
  }

  // per-lane x scalars (cond = c; harmless for invalid lanes)
  const float xs0 = x[c * 4 + 0], xs1 = x[c * 4 + 1];
  const float xt0 = x[c * 4 + 2], xt1 = x[c * 4 + 3];

  float rr[2][4], rsD[2][4], rsR[2][4];
  #pragma unroll
  for (int t2 = 0; t2 < 2; ++t2)
    #pragma unroll
    for (int k = 0; k < 4; ++k) { rr[t2][k] = 0.f; rsD[t2][k] = 0.f; rsR[t2][k] = 0.f; }

  __syncthreads();

  const uint32_t njbase = (uint32_t)(m * 128 + 32 * w + (lane & 31));
  const int rowU0 = 32 * w + 4 * kg;      // update-row base (tile t2 adds 16*t2)

  for (int ph = 0; ph < 5; ++ph) {
    // per-phase constant: cc[t2][k] = bias + input drive (rows 32w+16t2+4kg+k, cond c)
    float cc[2][4];
    #pragma unroll
    for (int t2 = 0; t2 < 2; ++t2) {
      const int row0 = rowU0 + 16 * t2;
      float4 b4 = *reinterpret_cast<const float4*>(&rec_b[(size_t)m * 128 + row0]);
      float bv[4] = {b4.x, b4.y, b4.z, b4.w};
      if (ph == 1 || ph == 3) {
        const float xa = (ph == 1) ? xs0 : xt0;
        const float xb = (ph == 1) ? xs1 : xt1;
        const float* ip = inp_w + ((size_t)m * 128 + row0) * 2;
        float4 iA = *reinterpret_cast<const float4*>(ip);      // w0[0],w1[0],w0[1],w1[1]
        float4 iB = *reinterpret_cast<const float4*>(ip + 4);
        cc[t2][0] = bv[0] + iA.x * xa + iA.y * xb;
        cc[t2][1] = bv[1] + iA.z * xa + iA.w * xb;
        cc[t2][2] = bv[2] + iB.x * xa + iB.y * xb;
        cc[t2][3] = bv[3] + iB.z * xa + iB.w * xb;
      } else {
        #pragma unroll
        for (int k = 0; k < 4; ++k) cc[t2][k] = bv[k];
      }
    }
    const bool phD = (ph == 2), phR = (ph == 4);

    for (int sp = 0; sp < 25; ++sp) {
      // noise: lane produces (row = lane&31 of this wave, substep = lane>>5)
      {
        uint2 key = sm.skeys[ph * 50 + 2 * sp + (lane >> 5)];
        uint2 bb = threefry(key.x, key.y, 0u, njbase);
        float nz = 0.1f * unit_from_bits(bb.x ^ bb.y);
        sm.nbuf[lane >> 5][32 * w + (lane & 31)] = nz;   // wave-local region
      }

      #pragma unroll
      for (int sub = 0; sub < 2; ++sub) {
        // --- B fragments (r) for this step
        bf16x8 B[4];
        if (n < 8) {
          #pragma unroll
          for (int q = 0; q < 4; ++q)
            B[q] = *reinterpret_cast<const bf16x8*>(&sm.bfrag[sub][q][kg][n][0]);
        } else {
          #pragma unroll
          for (int q = 0; q < 4; ++q) B[q] = (bf16x8)(short)0;
        }

        // --- MFMA: acc{t2} = (Whi+Wlo) @ B
        f32x4 acc0 = {0.f, 0.f, 0.f, 0.f}, acc1 = {0.f, 0.f, 0.f, 0.f};
        #pragma unroll
        for (int q = 0; q < 4; ++q)
          acc0 = __builtin_amdgcn_mfma_f32_16x16x32_bf16(whi[0][q], B[q], acc0, 0, 0, 0);
        #pragma unroll
        for (int q = 0; q < 4; ++q)
          acc0 = __builtin_amdgcn_mfma_f32_16x16x32_bf16(wlo[0][q], B[q], acc0, 0, 0, 0);
        #pragma unroll
        for (int q = 0; q < 4; ++q)
          acc1 = __builtin_amdgcn_mfma_f32_16x16x32_bf16(whi[1][q], B[q], acc1, 0, 0, 0);
        #pragma unroll
        for (int q = 0; q < 4; ++q)
          acc1 = __builtin_amdgcn_mfma_f32_16x16x32_bf16(wlo[1][q], B[q], acc1, 0, 0, 0);

        // --- combine hi/lo columns: pre[c] = col_c + col_{c+4}
        float comb[2][4];
        #pragma unroll
        for (int k = 0; k < 4; ++k) {
          comb[0][k] = acc0[k] + __shfl_xor(acc0[k], 4, 64);
          comb[1][k] = acc1[k] + __shfl_xor(acc1[k], 4, 64);
        }

        // --- update (valid data on lanes n<4; all lanes execute)
        float4 nz40 = *reinterpret_cast<const float4*>(&sm.nbuf[sub][rowU0]);
        float4 nz41 = *reinterpret_cast<const float4*>(&sm.nbuf[sub][rowU0 + 16]);
        float nzv[2][4] = {{nz40.x, nz40.y, nz40.z, nz40.w},
                           {nz41.x, nz41.y, nz41.z, nz41.w}};
        #pragma unroll
        for (int t2 = 0; t2 < 2; ++t2) {
          #pragma unroll
          for (int k = 0; k < 4; ++k) {
            float pre = comb[t2][k] + cc[t2][k];
            float rl = fmaxf(pre, 0.f);
            float d = rl + nzv[t2][k] - rr[t2][k];
            rr[t2][k] = fmaf(0.2f, d, rr[t2][k]);
          }
        }
        if (phD) {
          if ((sub == 0 && sp >= 13) || (sub == 1 && sp >= 12)) {
            #pragma unroll
            for (int t2 = 0; t2 < 2; ++t2)
              #pragma unroll
              for (int k = 0; k < 4; ++k) rsD[t2][k] += rr[t2][k];
          }
        }
        if (phR) {
          #pragma unroll
          for (int t2 = 0; t2 < 2; ++t2)
            #pragma unroll
            for (int k = 0; k < 4; ++k) rsR[t2][k] += rr[t2][k];
        }

        // --- split & write next-step fragments (cols c = rhi, c+4 = rlo)
        if (n < 4) {
          #pragma unroll
          for (int t2 = 0; t2 < 2; ++t2) {
            const int kgw = 2 * t2 + (kg >> 1);       // dest k-group
            const int e0 = 4 * (kg & 1);              // dest element base
            unsigned short hb[4], lb[4];
            #pragma unroll
            for (int k = 0; k < 4; ++k) {
              hb[k] = f2bf(rr[t2][k]);
              lb[k] = f2bf(rr[t2][k] - bf2f(hb[k]));
            }
            uint2 ph2 = make_uint2((uint32_t)hb[0] | ((uint32_t)hb[1] << 16),
                                   (uint32_t)hb[2] | ((uint32_t)hb[3] << 16));
            uint2 pl2 = make_uint2((uint32_t)lb[0] | ((uint32_t)lb[1] << 16),
                                   (uint32_t)lb[2] | ((uint32_t)lb[3] << 16));
            *reinterpret_cast<uint2*>(&sm.bfrag[sub ^ 1][w][kgw][c][e0]) = ph2;
            *reinterpret_cast<uint2*>(&sm.bfrag[sub ^ 1][w][kgw][c + 4][e0]) = pl2;
          }
        }
        __syncthreads();
      }
    }

    // --- phase-end projection (linear => project accumulated sums once)
    if (ph == 2 || ph == 4) {
      const float* pw = (ph == 2) ? mem_w : out_w;
      const float denom = (ph == 2) ? 25.0f : 50.0f;
      const int sel = (ph == 2) ? 0 : 1;
      float part[2] = {0.f, 0.f};
      #pragma unroll
      for (int t2 = 0; t2 < 2; ++t2) {
        const int row0 = rowU0 + 16 * t2;
        const float* rs = (ph == 2) ? rsD[t2] : rsR[t2];
        #pragma unroll
        for (int o = 0; o < 2; ++o) {
          float4 w4 = *reinterpret_cast<const float4*>(&pw[((size_t)m * 2 + o) * 128 + row0]);
          part[o] += w4.x * rs[0] + w4.y * rs[1] + w4.z * rs[2] + w4.w * rs[3];
        }
      }
      #pragma unroll
      for (int o = 0; o < 2; ++o) {
        part[o] += __shfl_xor(part[o], 16, 64);
        part[o] += __shfl_xor(part[o], 32, 64);
      }
      if (lane < 4) {
        sm.red[w][lane][0] = part[0];
        sm.red[w][lane][1] = part[1];
      }
      __syncthreads();
      if (t < 8) {
        int a = t >> 1, o = t & 1;
        float v = sm.red[0][a][o] + sm.red[1][a][o] + sm.red[2][a][o] + sm.red[3][a][o];
        out[(((size_t)sel * 4 + a) * 2048 + m) * 2 + o] = v / denom;
      }
      __syncthreads();
    }
  }
}

extern "C" void kernel_launch(void* const* d_in, const int* in_sizes, int n_in,
                              void* d_out, int out_size, void* d_ws, size_t ws_size,
                              hipStream_t stream) {
  (void)in_sizes; (void)n_in; (void)d_ws; (void)ws_size; (void)out_size;
  const float* x     = (const float*)d_in[0];
  const float* rec_w = (const float*)d_in[1];
  const float* rec_b = (const float*)d_in[2];
  const float* inp_w = (const float*)d_in[3];
  const float* out_w = (const float*)d_in[4];
  const float* mem_w = (const float*)d_in[5];
  rnn_kernel<<<2048, 256, 0, stream>>>(x, rec_w, rec_b, inp_w, out_w, mem_w, (float*)d_out);
}

// Round 6
// 625.291 us; speedup vs baseline: 5.4738x; 1.1689x over previous
//
#include <hip/hip_runtime.h>
#include <stdint.h>

// RNN ensemble: M=2048 models, N=128, A=4 conds, 5 phases x 50 steps.
// Block = 1 model, 4 waves. Wave w owns rows 32w..32w+31 (2 M-tiles).
// pre[128x4] = W @ r via mfma_f32_16x16x32_bf16, hi/lo bf16 split:
//   B cols 0-3 = rhi (4 conds), cols 4-7 = rlo; acc chains Whi@B then Wlo@B
//   => col_c + col_{c+4} (shfl_xor 4) = W@rhi + W@rlo (incl lo*lo, free).
// Lanes n<4 and n in 4..7 hold IDENTICAL pre/rr (col_c + col_{c^4} symmetric),
// so n<4 lanes write hi fragments and n in 4..7 write lo fragments.
// B reads are branchless: lanes n>=8 read col n&7 (dup data, results unused --
// they feed B cols 8..15 which only affect C cols 8..15, never read).
// R6 fix vs R5: zero-init exactly bfrag's 4KB (R5 zeroed 16KB, racing over
// skeys/nbuf and past the struct -> wrong noise -> absmax 7e-3).

typedef __attribute__((ext_vector_type(8))) short bf16x8;
typedef __attribute__((ext_vector_type(4))) float f32x4;

struct __align__(16) Smem {
  unsigned short bfrag[2][4][4][8][8]; // [parity][q][kg][col][e] bf16, 4KB
  float nbuf[2][128];                  // [substep][row] 0.02-scaled noise, 1KB
  uint2 skeys[250];
  float red[4][4][2];                  // [wave][cond][o]
};

__device__ __forceinline__ void tfround(uint32_t& x0, uint32_t& x1, const int r) {
  x0 += x1;
  x1 = (x1 << r) | (x1 >> (32 - r));
  x1 ^= x0;
}

// JAX threefry2x32 (20 rounds)
__device__ __forceinline__ uint2 threefry(uint32_t k0, uint32_t k1, uint32_t c0, uint32_t c1) {
  uint32_t k2 = k0 ^ k1 ^ 0x1BD11BDAu;
  uint32_t x0 = c0 + k0, x1 = c1 + k1;
  tfround(x0,x1,13); tfround(x0,x1,15); tfround(x0,x1,26); tfround(x0,x1,6);
  x0 += k1; x1 += k2 + 1u;
  tfround(x0,x1,17); tfround(x0,x1,29); tfround(x0,x1,16); tfround(x0,x1,24);
  x0 += k2; x1 += k0 + 2u;
  tfround(x0,x1,13); tfround(x0,x1,15); tfround(x0,x1,26); tfround(x0,x1,6);
  x0 += k0; x1 += k1 + 3u;
  tfround(x0,x1,17); tfround(x0,x1,29); tfround(x0,x1,16); tfround(x0,x1,24);
  x0 += k1; x1 += k2 + 4u;
  tfround(x0,x1,13); tfround(x0,x1,15); tfround(x0,x1,26); tfround(x0,x1,6);
  x0 += k2; x1 += k0 + 5u;
  return make_uint2(x0, x1);
}

__device__ __forceinline__ float unit_from_bits(uint32_t bits) {
  return __uint_as_float((bits >> 9) | 0x3f800000u) - 1.0f;
}

__device__ __forceinline__ unsigned short f2bf(float f) {
  uint32_t u = __float_as_uint(f);
  uint32_t r = u + 0x7fffu + ((u >> 16) & 1u);   // RNE (non-NaN inputs)
  return (unsigned short)(r >> 16);
}
__device__ __forceinline__ float bf2f(unsigned short b) {
  return __uint_as_float(((uint32_t)b) << 16);
}
// packed f32x2 -> bf16x2 (D[15:0]=bf16(a), D[31:16]=bf16(b))
__device__ __forceinline__ uint32_t cvt_pk_bf16(float a, float b) {
  uint32_t r;
  asm("v_cvt_pk_bf16_f32 %0, %1, %2" : "=v"(r) : "v"(a), "v"(b));
  return r;
}

__global__ __launch_bounds__(256, 3) void rnn_kernel(
    const float* __restrict__ x,
    const float* __restrict__ rec_w,
    const float* __restrict__ rec_b,
    const float* __restrict__ inp_w,
    const float* __restrict__ out_w,
    const float* __restrict__ mem_w,
    float* __restrict__ out) {
  __shared__ Smem sm;
  const int t = threadIdx.x;
  const int m = blockIdx.x;
  const int w = t >> 6;          // wave 0..3
  const int lane = t & 63;
  const int n = lane & 15;       // A-row / B-col / C-col index within tile
  const int kg = lane >> 4;      // k-group (0..3)
  const int c = n & 3;           // cond id

  // step keys
  if (t < 250) {
    int p = t / 50, s = t - p * 50;
    uint2 pk = threefry(0u, 42u, 0u, (uint32_t)p);
    sm.skeys[t] = threefry(pk.x, pk.y, 0u, (uint32_t)s);
  }
  // zero the fragment buffer: exactly 4KB = 256 threads x 16B
  {
    uint4* bz = reinterpret_cast<uint4*>(&sm.bfrag[0][0][0][0][0]);
    bz[t] = make_uint4(0u, 0u, 0u, 0u);
  }

  // --- W fragments into registers: whi/wlo[t2][q], row = 32w+16*t2+n, k = 32q+8kg+e
  bf16x8 whi[2][4], wlo[2][4];
  #pragma unroll
  for (int t2 = 0; t2 < 2; ++t2) {
    const int rowA = 32 * w + 16 * t2 + n;
    const float* gp = rec_w + (size_t)m * 16384 + (size_t)rowA * 128 + 8 * kg;
    #pragma unroll
    for (int q = 0; q < 4; ++q) {
      float4 f0 = *reinterpret_cast<const float4*>(gp + 32 * q);
      float4 f1 = *reinterpret_cast<const float4*>(gp + 32 * q + 4);
      float fv[8] = {f0.x, f0.y, f0.z, f0.w, f1.x, f1.y, f1.z, f1.w};
      bf16x8 vh, vl;
      #pragma unroll
      for (int e = 0; e < 8; ++e) {
        unsigned short hb = f2bf(fv[e]);
        vh[e] = (short)hb;
        vl[e] = (short)f2bf(fv[e] - bf2f(hb));
      }
      whi[t2][q] = vh;
      wlo[t2][q] = vl;
    }
  }

  // per-lane x scalars (cond = c)
  const float xs0 = x[c * 4 + 0], xs1 = x[c * 4 + 1];
  const float xt0 = x[c * 4 + 2], xt1 = x[c * 4 + 3];

  float rr[2][4], rsD[2][4], rsR[2][4];
  #pragma unroll
  for (int t2 = 0; t2 < 2; ++t2)
    #pragma unroll
    for (int k = 0; k < 4; ++k) { rr[t2][k] = 0.f; rsD[t2][k] = 0.f; rsR[t2][k] = 0.f; }

  __syncthreads();

  const uint32_t njbase = (uint32_t)(m * 128 + 32 * w + (lane & 31));
  const int rowU0 = 32 * w + 4 * kg;      // update-row base (tile t2 adds 16*t2)

  for (int ph = 0; ph < 5; ++ph) {
    // cc[t2][k] = bias + input drive (rows 32w+16t2+4kg+k, cond c)
    float cc[2][4];
    #pragma unroll
    for (int t2 = 0; t2 < 2; ++t2) {
      const int row0 = rowU0 + 16 * t2;
      float4 b4 = *reinterpret_cast<const float4*>(&rec_b[(size_t)m * 128 + row0]);
      float bv[4] = {b4.x, b4.y, b4.z, b4.w};
      if (ph == 1 || ph == 3) {
        const float xa = (ph == 1) ? xs0 : xt0;
        const float xb = (ph == 1) ? xs1 : xt1;
        const float* ip = inp_w + ((size_t)m * 128 + row0) * 2;
        float4 iA = *reinterpret_cast<const float4*>(ip);
        float4 iB = *reinterpret_cast<const float4*>(ip + 4);
        cc[t2][0] = bv[0] + iA.x * xa + iA.y * xb;
        cc[t2][1] = bv[1] + iA.z * xa + iA.w * xb;
        cc[t2][2] = bv[2] + iB.x * xa + iB.y * xb;
        cc[t2][3] = bv[3] + iB.z * xa + iB.w * xb;
      } else {
        #pragma unroll
        for (int k = 0; k < 4; ++k) cc[t2][k] = bv[k];
      }
    }
    const bool phD = (ph == 2), phR = (ph == 4);

    for (int sp = 0; sp < 25; ++sp) {
      // noise (0.02-scaled): lane -> (row = lane&31, substep = lane>>5)
      {
        uint2 key = sm.skeys[ph * 50 + 2 * sp + (lane >> 5)];
        uint2 bb = threefry(key.x, key.y, 0u, njbase);
        sm.nbuf[lane >> 5][32 * w + (lane & 31)] = 0.02f * unit_from_bits(bb.x ^ bb.y);
      }

      #pragma unroll
      for (int sub = 0; sub < 2; ++sub) {
        // --- B fragments: branchless; lanes n>=8 read duplicate cols (ignored)
        bf16x8 B[4];
        #pragma unroll
        for (int q = 0; q < 4; ++q)
          B[q] = *reinterpret_cast<const bf16x8*>(&sm.bfrag[sub][q][kg][n & 7][0]);

        // --- MFMA: acc{t2} = (Whi+Wlo) @ B
        f32x4 acc0 = {0.f, 0.f, 0.f, 0.f}, acc1 = {0.f, 0.f, 0.f, 0.f};
        #pragma unroll
        for (int q = 0; q < 4; ++q)
          acc0 = __builtin_amdgcn_mfma_f32_16x16x32_bf16(whi[0][q], B[q], acc0, 0, 0, 0);
        #pragma unroll
        for (int q = 0; q < 4; ++q)
          acc0 = __builtin_amdgcn_mfma_f32_16x16x32_bf16(wlo[0][q], B[q], acc0, 0, 0, 0);
        #pragma unroll
        for (int q = 0; q < 4; ++q)
          acc1 = __builtin_amdgcn_mfma_f32_16x16x32_bf16(whi[1][q], B[q], acc1, 0, 0, 0);
        #pragma unroll
        for (int q = 0; q < 4; ++q)
          acc1 = __builtin_amdgcn_mfma_f32_16x16x32_bf16(wlo[1][q], B[q], acc1, 0, 0, 0);

        // --- combine hi/lo columns: pre[c] = col_c + col_{c^4} (symmetric)
        float comb[2][4];
        #pragma unroll
        for (int k = 0; k < 4; ++k) {
          comb[0][k] = acc0[k] + __shfl_xor(acc0[k], 4, 64);
          comb[1][k] = acc1[k] + __shfl_xor(acc1[k], 4, 64);
        }

        // --- update (valid rr on lanes n<8; all lanes execute)
        float4 nz40 = *reinterpret_cast<const float4*>(&sm.nbuf[sub][rowU0]);
        float4 nz41 = *reinterpret_cast<const float4*>(&sm.nbuf[sub][rowU0 + 16]);
        float nzv[2][4] = {{nz40.x, nz40.y, nz40.z, nz40.w},
                           {nz41.x, nz41.y, nz41.z, nz41.w}};
        #pragma unroll
        for (int t2 = 0; t2 < 2; ++t2) {
          #pragma unroll
          for (int k = 0; k < 4; ++k) {
            float pre = comb[t2][k] + cc[t2][k];
            float rl = fmaxf(pre, 0.f);
            rr[t2][k] = fmaf(0.8f, rr[t2][k], fmaf(0.2f, rl, nzv[t2][k]));
          }
        }
        if (phD) {
          if ((sub == 0 && sp >= 13) || (sub == 1 && sp >= 12)) {
            #pragma unroll
            for (int t2 = 0; t2 < 2; ++t2)
              #pragma unroll
              for (int k = 0; k < 4; ++k) rsD[t2][k] += rr[t2][k];
          }
        }
        if (phR) {
          #pragma unroll
          for (int t2 = 0; t2 < 2; ++t2)
            #pragma unroll
            for (int k = 0; k < 4; ++k) rsR[t2][k] += rr[t2][k];
        }

        // --- split & write next-step fragments: n<4 lanes write hi (col c),
        //     n in 4..7 write lo (col c+4). rr identical across the pair.
        if (n < 8) {
          #pragma unroll
          for (int t2 = 0; t2 < 2; ++t2) {
            const int kgw = 2 * t2 + (kg >> 1);       // dest k-group
            const int e0 = 4 * (kg & 1);              // dest element base
            uint32_t h0 = cvt_pk_bf16(rr[t2][0], rr[t2][1]);
            uint32_t h1 = cvt_pk_bf16(rr[t2][2], rr[t2][3]);
            if (n < 4) {
              *reinterpret_cast<uint2*>(&sm.bfrag[sub ^ 1][w][kgw][c][e0]) =
                  make_uint2(h0, h1);
            } else {
              float l0 = rr[t2][0] - __uint_as_float(h0 << 16);
              float l1 = rr[t2][1] - __uint_as_float(h0 & 0xffff0000u);
              float l2 = rr[t2][2] - __uint_as_float(h1 << 16);
              float l3 = rr[t2][3] - __uint_as_float(h1 & 0xffff0000u);
              uint32_t p0 = cvt_pk_bf16(l0, l1);
              uint32_t p1 = cvt_pk_bf16(l2, l3);
              *reinterpret_cast<uint2*>(&sm.bfrag[sub ^ 1][w][kgw][c + 4][e0]) =
                  make_uint2(p0, p1);
            }
          }
        }
        __syncthreads();
      }
    }

    // --- phase-end projection (linear => project accumulated sums once)
    if (ph == 2 || ph == 4) {
      const float* pw = (ph == 2) ? mem_w : out_w;
      const float denom = (ph == 2) ? 25.0f : 50.0f;
      const int sel = (ph == 2) ? 0 : 1;
      float part[2] = {0.f, 0.f};
      #pragma unroll
      for (int t2 = 0; t2 < 2; ++t2) {
        const int row0 = rowU0 + 16 * t2;
        const float* rs = (ph == 2) ? rsD[t2] : rsR[t2];
        #pragma unroll
        for (int o = 0; o < 2; ++o) {
          float4 w4 = *reinterpret_cast<const float4*>(&pw[((size_t)m * 2 + o) * 128 + row0]);
          part[o] += w4.x * rs[0] + w4.y * rs[1] + w4.z * rs[2] + w4.w * rs[3];
        }
      }
      #pragma unroll
      for (int o = 0; o < 2; ++o) {
        part[o] += __shfl_xor(part[o], 16, 64);
        part[o] += __shfl_xor(part[o], 32, 64);
      }
      if (lane < 4) {
        sm.red[w][lane][0] = part[0];
        sm.red[w][lane][1] = part[1];
      }
      __syncthreads();
      if (t < 8) {
        int a = t >> 1, o = t & 1;
        float v = sm.red[0][a][o] + sm.red[1][a][o] + sm.red[2][a][o] + sm.red[3][a][o];
        out[(((size_t)sel * 4 + a) * 2048 + m) * 2 + o] = v / denom;
      }
      __syncthreads();
    }
  }
}

extern "C" void kernel_launch(void* const* d_in, const int* in_sizes, int n_in,
                              void* d_out, int out_size, void* d_ws, size_t ws_size,
                              hipStream_t stream) {
  (void)in_sizes; (void)n_in; (void)d_ws; (void)ws_size; (void)out_size;
  const float* x     = (const float*)d_in[0];
  const float* rec_w = (const float*)d_in[1];
  const float* rec_b = (const float*)d_in[2];
  const float* inp_w = (const float*)d_in[3];
  const float* out_w = (const float*)d_in[4];
  const float* mem_w = (const float*)d_in[5];
  rnn_kernel<<<2048, 256, 0, stream>>>(x, rec_w, rec_b, inp_w, out_w, mem_w, (float*)d_out);
}

// Round 7
// 538.023 us; speedup vs baseline: 6.3617x; 1.1622x over previous
//
#include <hip/hip_runtime.h>
#include <stdint.h>

// RNN ensemble: M=2048 models, N=128, A=4 conds, 5 phases x 50 steps.
// Block = 1 model, 4 waves. Wave w owns rows 32w..32w+31 (2 M-tiles).
// pre[128x4] = W @ r via mfma_f32_16x16x32_bf16, hi/lo bf16 split:
//   B cols 0-3 = rhi (4 conds), cols 4-7 = rlo; acc chains Whi@B then Wlo@B
//   => comb = col_c + col_{c^4} (shfl_xor 4) = cc + W@rhi + W@rlo.
// Lanes n>=8 read B col n&7 so acc cols 8-15 MIRROR cols 0-7 -> every lane
// holds a valid comb. R7: per-lane tile ownership: lane handles only tile
// t2sel=n>>3 (update/split/noise halved); bias+input cc folded into the MFMA
// C-init (ccm = lohalf ? 0 : cc, so the col-pair sum carries cc exactly once);
// all 64 lanes write one uint2 fragment (bijective (kgw,col,e0) <-> lane map).

typedef __attribute__((ext_vector_type(8))) short bf16x8;
typedef __attribute__((ext_vector_type(4))) float f32x4;

struct __align__(16) Smem {
  unsigned short bfrag[2][4][4][8][8]; // [parity][q][kg][col][e] bf16, 4KB
  float nbuf[2][128];                  // [substep][row] 0.02-scaled noise, 1KB
  uint2 skeys[250];
  float red[4][4][2];                  // [wave][cond][o]
};

__device__ __forceinline__ void tfround(uint32_t& x0, uint32_t& x1, const int r) {
  x0 += x1;
  x1 = (x1 << r) | (x1 >> (32 - r));
  x1 ^= x0;
}

// JAX threefry2x32 (20 rounds)
__device__ __forceinline__ uint2 threefry(uint32_t k0, uint32_t k1, uint32_t c0, uint32_t c1) {
  uint32_t k2 = k0 ^ k1 ^ 0x1BD11BDAu;
  uint32_t x0 = c0 + k0, x1 = c1 + k1;
  tfround(x0,x1,13); tfround(x0,x1,15); tfround(x0,x1,26); tfround(x0,x1,6);
  x0 += k1; x1 += k2 + 1u;
  tfround(x0,x1,17); tfround(x0,x1,29); tfround(x0,x1,16); tfround(x0,x1,24);
  x0 += k2; x1 += k0 + 2u;
  tfround(x0,x1,13); tfround(x0,x1,15); tfround(x0,x1,26); tfround(x0,x1,6);
  x0 += k0; x1 += k1 + 3u;
  tfround(x0,x1,17); tfround(x0,x1,29); tfround(x0,x1,16); tfround(x0,x1,24);
  x0 += k1; x1 += k2 + 4u;
  tfround(x0,x1,13); tfround(x0,x1,15); tfround(x0,x1,26); tfround(x0,x1,6);
  x0 += k2; x1 += k0 + 5u;
  return make_uint2(x0, x1);
}

__device__ __forceinline__ float unit_from_bits(uint32_t bits) {
  return __uint_as_float((bits >> 9) | 0x3f800000u) - 1.0f;
}

__device__ __forceinline__ unsigned short f2bf(float f) {
  uint32_t u = __float_as_uint(f);
  uint32_t r = u + 0x7fffu + ((u >> 16) & 1u);   // RNE (non-NaN inputs)
  return (unsigned short)(r >> 16);
}
__device__ __forceinline__ float bf2f(unsigned short b) {
  return __uint_as_float(((uint32_t)b) << 16);
}
// packed f32x2 -> bf16x2 (D[15:0]=bf16(a), D[31:16]=bf16(b))
__device__ __forceinline__ uint32_t cvt_pk_bf16(float a, float b) {
  uint32_t r;
  asm("v_cvt_pk_bf16_f32 %0, %1, %2" : "=v"(r) : "v"(a), "v"(b));
  return r;
}

__global__ __launch_bounds__(256, 4) void rnn_kernel(
    const float* __restrict__ x,
    const float* __restrict__ rec_w,
    const float* __restrict__ rec_b,
    const float* __restrict__ inp_w,
    const float* __restrict__ out_w,
    const float* __restrict__ mem_w,
    float* __restrict__ out) {
  __shared__ Smem sm;
  const int t = threadIdx.x;
  const int m = blockIdx.x;
  const int w = t >> 6;          // wave 0..3
  const int lane = t & 63;
  const int n = lane & 15;       // A-row / B-col / C-col index within tile
  const int kg = lane >> 4;      // k-group (0..3)
  const int c = n & 3;           // cond id
  const int t2sel = n >> 3;      // owned M-tile (0: rows +0..15, 1: +16..31)
  const int lohalf = (n >> 2) & 1;  // 0 = hi-fragment writer, 1 = lo writer

  // step keys
  if (t < 250) {
    int p = t / 50, s = t - p * 50;
    uint2 pk = threefry(0u, 42u, 0u, (uint32_t)p);
    sm.skeys[t] = threefry(pk.x, pk.y, 0u, (uint32_t)s);
  }
  // zero the fragment buffer: exactly 4KB = 256 threads x 16B
  {
    uint4* bz = reinterpret_cast<uint4*>(&sm.bfrag[0][0][0][0][0]);
    bz[t] = make_uint4(0u, 0u, 0u, 0u);
  }

  // --- W fragments into registers: whi/wlo[t2][q], row = 32w+16*t2+n, k = 32q+8kg+e
  bf16x8 whi[2][4], wlo[2][4];
  #pragma unroll
  for (int t2 = 0; t2 < 2; ++t2) {
    const int rowA = 32 * w + 16 * t2 + n;
    const float* gp = rec_w + (size_t)m * 16384 + (size_t)rowA * 128 + 8 * kg;
    #pragma unroll
    for (int q = 0; q < 4; ++q) {
      float4 f0 = *reinterpret_cast<const float4*>(gp + 32 * q);
      float4 f1 = *reinterpret_cast<const float4*>(gp + 32 * q + 4);
      float fv[8] = {f0.x, f0.y, f0.z, f0.w, f1.x, f1.y, f1.z, f1.w};
      bf16x8 vh, vl;
      #pragma unroll
      for (int e = 0; e < 8; ++e) {
        unsigned short hb = f2bf(fv[e]);
        vh[e] = (short)hb;
        vl[e] = (short)f2bf(fv[e] - bf2f(hb));
      }
      whi[t2][q] = vh;
      wlo[t2][q] = vl;
    }
  }

  // per-lane x scalars (cond = c)
  const float xs0 = x[c * 4 + 0], xs1 = x[c * 4 + 1];
  const float xt0 = x[c * 4 + 2], xt1 = x[c * 4 + 3];

  // owned rows: rowU..rowU+3 (cond c)
  const int rowU = 32 * w + 4 * kg + 16 * t2sel;

  float rr[4] = {0.f, 0.f, 0.f, 0.f};
  float rsD[4] = {0.f, 0.f, 0.f, 0.f};
  float rsR[4] = {0.f, 0.f, 0.f, 0.f};

  __syncthreads();

  const uint32_t njbase = (uint32_t)(m * 128 + 32 * w + (lane & 31));

  for (int ph = 0; ph < 5; ++ph) {
    // ccm = (bias + input drive) for owned rows, masked to hi lanes only:
    // it seeds the MFMA C-init so the hi+lo column-pair sum carries cc once.
    f32x4 ccv;
    {
      float4 b4 = *reinterpret_cast<const float4*>(&rec_b[(size_t)m * 128 + rowU]);
      float cc[4] = {b4.x, b4.y, b4.z, b4.w};
      if (ph == 1 || ph == 3) {
        const float xa = (ph == 1) ? xs0 : xt0;
        const float xb = (ph == 1) ? xs1 : xt1;
        const float* ip = inp_w + ((size_t)m * 128 + rowU) * 2;
        float4 iA = *reinterpret_cast<const float4*>(ip);
        float4 iB = *reinterpret_cast<const float4*>(ip + 4);
        cc[0] += iA.x * xa + iA.y * xb;
        cc[1] += iA.z * xa + iA.w * xb;
        cc[2] += iB.x * xa + iB.y * xb;
        cc[3] += iB.z * xa + iB.w * xb;
      }
      #pragma unroll
      for (int k = 0; k < 4; ++k) ccv[k] = lohalf ? 0.f : cc[k];
    }
    const bool phD = (ph == 2), phR = (ph == 4);

    for (int sp = 0; sp < 25; ++sp) {
      // noise (0.02-scaled): lane -> (row = lane&31, substep = lane>>5)
      {
        uint2 key = sm.skeys[ph * 50 + 2 * sp + (lane >> 5)];
        uint2 bb = threefry(key.x, key.y, 0u, njbase);
        sm.nbuf[lane >> 5][32 * w + (lane & 31)] = 0.02f * unit_from_bits(bb.x ^ bb.y);
      }

      #pragma unroll
      for (int sub = 0; sub < 2; ++sub) {
        // --- B fragments: lanes n>=8 read col n&7 -> acc cols 8-15 mirror 0-7
        bf16x8 B[4];
        #pragma unroll
        for (int q = 0; q < 4; ++q)
          B[q] = *reinterpret_cast<const bf16x8*>(&sm.bfrag[sub][q][kg][n & 7][0]);

        // --- MFMA: acc{t2} = ccv + (Whi+Wlo) @ B
        f32x4 acc0 = ccv, acc1 = ccv;
        #pragma unroll
        for (int q = 0; q < 4; ++q)
          acc0 = __builtin_amdgcn_mfma_f32_16x16x32_bf16(whi[0][q], B[q], acc0, 0, 0, 0);
        #pragma unroll
        for (int q = 0; q < 4; ++q)
          acc0 = __builtin_amdgcn_mfma_f32_16x16x32_bf16(wlo[0][q], B[q], acc0, 0, 0, 0);
        #pragma unroll
        for (int q = 0; q < 4; ++q)
          acc1 = __builtin_amdgcn_mfma_f32_16x16x32_bf16(whi[1][q], B[q], acc1, 0, 0, 0);
        #pragma unroll
        for (int q = 0; q < 4; ++q)
          acc1 = __builtin_amdgcn_mfma_f32_16x16x32_bf16(wlo[1][q], B[q], acc1, 0, 0, 0);

        // --- select own tile's acc; pre = col_c + col_{c^4} (carries cc once)
        float4 nz4 = *reinterpret_cast<const float4*>(&sm.nbuf[sub][rowU]);
        float nzv[4] = {nz4.x, nz4.y, nz4.z, nz4.w};
        #pragma unroll
        for (int k = 0; k < 4; ++k) {
          float aS = t2sel ? acc1[k] : acc0[k];
          float pre = aS + __shfl_xor(aS, 4, 64);
          float rl = fmaxf(pre, 0.f);
          rr[k] = fmaf(0.8f, rr[k], fmaf(0.2f, rl, nzv[k]));
        }
        if (phD) {
          if ((sub == 0 && sp >= 13) || (sub == 1 && sp >= 12)) {
            #pragma unroll
            for (int k = 0; k < 4; ++k) rsD[k] += rr[k];
          }
        }
        if (phR) {
          #pragma unroll
          for (int k = 0; k < 4; ++k) rsR[k] += rr[k];
        }

        // --- split & write next-step fragment: every lane writes one uint2.
        // dest (kgw,col,e0) <-> lane (t2sel,kg,lohalf,c) is bijective.
        {
          const int kgw = 2 * t2sel + (kg >> 1);
          const int e0 = 4 * (kg & 1);
          const int col = c + 4 * lohalf;
          uint32_t h0 = cvt_pk_bf16(rr[0], rr[1]);
          uint32_t h1 = cvt_pk_bf16(rr[2], rr[3]);
          uint2 pk2;
          if (!lohalf) {
            pk2 = make_uint2(h0, h1);
          } else {
            float l0 = rr[0] - __uint_as_float(h0 << 16);
            float l1 = rr[1] - __uint_as_float(h0 & 0xffff0000u);
            float l2 = rr[2] - __uint_as_float(h1 << 16);
            float l3 = rr[3] - __uint_as_float(h1 & 0xffff0000u);
            pk2 = make_uint2(cvt_pk_bf16(l0, l1), cvt_pk_bf16(l2, l3));
          }
          *reinterpret_cast<uint2*>(&sm.bfrag[sub ^ 1][w][kgw][col][e0]) = pk2;
        }
        __syncthreads();
      }
    }

    // --- phase-end projection (linear => project accumulated sums once)
    if (ph == 2 || ph == 4) {
      const float* pw = (ph == 2) ? mem_w : out_w;
      const float denom = (ph == 2) ? 25.0f : 50.0f;
      const int sel = (ph == 2) ? 0 : 1;
      const float* rs = (ph == 2) ? rsD : rsR;
      float part[2];
      #pragma unroll
      for (int o = 0; o < 2; ++o) {
        float4 w4 = *reinterpret_cast<const float4*>(&pw[((size_t)m * 2 + o) * 128 + rowU]);
        part[o] = w4.x * rs[0] + w4.y * rs[1] + w4.z * rs[2] + w4.w * rs[3];
      }
      // reduce: xor8 merges t2 partners; xor16/32 merge kg. n&7 classes stay
      // separate, so hi/lo duplicate lanes never double-count.
      #pragma unroll
      for (int o = 0; o < 2; ++o) {
        part[o] += __shfl_xor(part[o], 8, 64);
        part[o] += __shfl_xor(part[o], 16, 64);
        part[o] += __shfl_xor(part[o], 32, 64);
      }
      if (lane < 4) {
        sm.red[w][lane][0] = part[0];
        sm.red[w][lane][1] = part[1];
      }
      __syncthreads();
      if (t < 8) {
        int a = t >> 1, o = t & 1;
        float v = sm.red[0][a][o] + sm.red[1][a][o] + sm.red[2][a][o] + sm.red[3][a][o];
        out[(((size_t)sel * 4 + a) * 2048 + m) * 2 + o] = v / denom;
      }
      __syncthreads();
    }
  }
}

extern "C" void kernel_launch(void* const* d_in, const int* in_sizes, int n_in,
                              void* d_out, int out_size, void* d_ws, size_t ws_size,
                              hipStream_t stream) {
  (void)in_sizes; (void)n_in; (void)d_ws; (void)ws_size; (void)out_size;
  const float* x     = (const float*)d_in[0];
  const float* rec_w = (const float*)d_in[1];
  const float* rec_b = (const float*)d_in[2];
  const float* inp_w = (const float*)d_in[3];
  const float* out_w = (const float*)d_in[4];
  const float* mem_w = (const float*)d_in[5];
  rnn_kernel<<<2048, 256, 0, stream>>>(x, rec_w, rec_b, inp_w, out_w, mem_w, (float*)d_out);
}